// Round 1
// baseline (1356.653 us; speedup 1.0000x reference)
//
#include <hip/hip_runtime.h>
#include <hip/hip_bf16.h>

typedef __bf16 bf16_t;
typedef bf16_t bf16x8 __attribute__((ext_vector_type(8)));
typedef bf16_t bf16x4v __attribute__((ext_vector_type(4)));
typedef bf16_t bf16x2v __attribute__((ext_vector_type(2)));
typedef float f32x4 __attribute__((ext_vector_type(4)));

#define N_NODES 500000
#define N_GRAPHS 4096
#define NODE_SIZE 512
#define GLOBAL_SIZE 256
#define HIDDEN_SIZE 1024
#define INPUT_SIZE 768

__device__ __forceinline__ void async16(const bf16_t* g, bf16_t* l) {
    __builtin_amdgcn_global_load_lds(
        (__attribute__((address_space(1))) void*)(const_cast<bf16_t*>(g)),
        (__attribute__((address_space(3))) void*)(l), 16, 0, 0);
}

// ---------------------------------------------------------------------------
// Weight convert+transpose: W[K][N] f32 -> Wt[N][K] bf16. Small (<=3MB read),
// uncoalesced reads absorbed by L2.
// ---------------------------------------------------------------------------
__global__ void cvt_transpose(const float* __restrict__ W, bf16_t* __restrict__ Wt,
                              int K, int N) {
    int idx = blockIdx.x * blockDim.x + threadIdx.x;
    if (idx >= N * K) return;
    int n = idx / K, k = idx - n * K;
    Wt[idx] = (bf16_t)W[k * N + n];
}

// ---------------------------------------------------------------------------
// Per-graph mean of x rows (batch sorted -> contiguous segment per graph),
// fused with concat: A[g] = [bf16(u[g]) | bf16(mean_g)]  (A is [4096][768] bf16)
// One block (128 threads) per graph; float4 streaming loads (16 B/lane).
// ---------------------------------------------------------------------------
__global__ __launch_bounds__(128)
void mean_concat_kernel(const float* __restrict__ x, const float* __restrict__ u,
                        const int* __restrict__ batch, bf16_t* __restrict__ A) {
    const int g = blockIdx.x;
    const int tid = threadIdx.x;

    // u part: 256 floats -> bf16, 2 per thread
    {
        const float2 uv = *(const float2*)(u + (size_t)g * GLOBAL_SIZE + tid * 2);
        bf16x2v o;
        o[0] = (bf16_t)uv.x;
        o[1] = (bf16_t)uv.y;
        *(bf16x2v*)(A + (size_t)g * INPUT_SIZE + tid * 2) = o;
    }

    // segment bounds via binary search (uniform across threads)
    int start, end;
    {
        int lo = 0, hi = N_NODES;
        while (lo < hi) { int m = (lo + hi) >> 1; if (batch[m] < g) lo = m + 1; else hi = m; }
        start = lo;
        hi = N_NODES;
        while (lo < hi) { int m = (lo + hi) >> 1; if (batch[m] < g + 1) lo = m + 1; else hi = m; }
        end = lo;
    }

    // accumulate 4 columns per thread, 2-row unroll for outstanding loads
    float4 s0 = make_float4(0.f, 0.f, 0.f, 0.f);
    float4 s1 = make_float4(0.f, 0.f, 0.f, 0.f);
    int r = start;
    for (; r + 1 < end; r += 2) {
        const float4 v0 = *(const float4*)(x + (size_t)r * NODE_SIZE + tid * 4);
        const float4 v1 = *(const float4*)(x + (size_t)(r + 1) * NODE_SIZE + tid * 4);
        s0.x += v0.x; s0.y += v0.y; s0.z += v0.z; s0.w += v0.w;
        s1.x += v1.x; s1.y += v1.y; s1.z += v1.z; s1.w += v1.w;
    }
    if (r < end) {
        const float4 v0 = *(const float4*)(x + (size_t)r * NODE_SIZE + tid * 4);
        s0.x += v0.x; s0.y += v0.y; s0.z += v0.z; s0.w += v0.w;
    }
    const int cnt = end - start;
    const float inv = cnt > 0 ? 1.f / (float)cnt : 0.f;
    bf16x4v o;
    o[0] = (bf16_t)((s0.x + s1.x) * inv);
    o[1] = (bf16_t)((s0.y + s1.y) * inv);
    o[2] = (bf16_t)((s0.z + s1.z) * inv);
    o[3] = (bf16_t)((s0.w + s1.w) * inv);
    *(bf16x4v*)(A + (size_t)g * INPUT_SIZE + GLOBAL_SIZE + tid * 4) = o;
}

// ---------------------------------------------------------------------------
// GEMM: C[M][N] = act(A[M][K] @ Bt[N][K]^T + bias), bf16 inputs, fp32 acc.
// m97 recipe: 128x128 tile, BK=32, global_load_lds width-16, mfma 16x16x32.
// 4 waves in 2x2, each wave 64x64 via 4x4 mfma accs.
// ---------------------------------------------------------------------------
template <bool SELU_ACT, bool OUT_BF16>
__global__ __launch_bounds__(256)
void gemm_bt(const bf16_t* __restrict__ A, const bf16_t* __restrict__ Bt,
             const float* __restrict__ bias, void* __restrict__ Cv,
             int M, int N, int K) {
    constexpr int BM = 128, BN = 128, BK = 32;
    __shared__ bf16_t Al[BM * BK];
    __shared__ bf16_t Bl[BN * BK];

    const int tid = threadIdx.x;
    const int wave = tid >> 6, lane = tid & 63;
    const int quad = lane >> 4, rr = lane & 15;
    const int wm = (wave >> 1) * 64, wn = (wave & 1) * 64;
    const int tm = blockIdx.x * BM, tn = blockIdx.y * BN;

    f32x4 acc[4][4] = {};

    for (int bk = 0; bk < K; bk += BK) {
        // stage A tile: 128 rows x 32 cols bf16 = 512 x 16B chunks, 2/thread
#pragma unroll
        for (int i = 0; i < 2; ++i) {
            int linear = i * 256 + tid;
            int row = linear >> 2, kq = linear & 3;
            async16(A + (size_t)(tm + row) * K + bk + kq * 8, &Al[linear * 8]);
        }
#pragma unroll
        for (int i = 0; i < 2; ++i) {
            int linear = i * 256 + tid;
            int row = linear >> 2, kq = linear & 3;
            async16(Bt + (size_t)(tn + row) * K + bk + kq * 8, &Bl[linear * 8]);
        }
        __syncthreads();  // drains vmcnt incl. global_load_lds

        bf16x8 af[4], bfr[4];
#pragma unroll
        for (int mi = 0; mi < 4; ++mi)
            af[mi] = *(const bf16x8*)&Al[(wm + mi * 16 + rr) * BK + quad * 8];
#pragma unroll
        for (int ni = 0; ni < 4; ++ni)
            bfr[ni] = *(const bf16x8*)&Bl[(wn + ni * 16 + rr) * BK + quad * 8];
#pragma unroll
        for (int mi = 0; mi < 4; ++mi)
#pragma unroll
            for (int ni = 0; ni < 4; ++ni)
                acc[mi][ni] = __builtin_amdgcn_mfma_f32_16x16x32_bf16(
                    af[mi], bfr[ni], acc[mi][ni], 0, 0, 0);
        __syncthreads();
    }

    // epilogue: D row = quad*4+e, col = rr (per 16x16 sub-tile)
    float* Cf = (float*)Cv;
    bf16_t* Cb = (bf16_t*)Cv;
#pragma unroll
    for (int ni = 0; ni < 4; ++ni) {
        const int col = tn + wn + ni * 16 + rr;
        const float bv = bias[col];
#pragma unroll
        for (int mi = 0; mi < 4; ++mi) {
#pragma unroll
            for (int e = 0; e < 4; ++e) {
                const int row = tm + wm + mi * 16 + quad * 4 + e;
                float val = acc[mi][ni][e] + bv;
                if (SELU_ACT) {
                    val = val > 0.f ? 1.0507009873554805f * val
                                    : 1.7580993408473766f * (__expf(val) - 1.f);
                }
                if (OUT_BF16) Cb[(size_t)row * N + col] = (bf16_t)val;
                else          Cf[(size_t)row * N + col] = val;
            }
        }
    }
}

extern "C" void kernel_launch(void* const* d_in, const int* in_sizes, int n_in,
                              void* d_out, int out_size, void* d_ws, size_t ws_size,
                              hipStream_t stream) {
    const float* x     = (const float*)d_in[0];
    // d_in[1] edge_index, d_in[2] edge_attr: unused by reference
    const float* u     = (const float*)d_in[3];
    const int*   batch = (const int*)d_in[4];
    const float* W1    = (const float*)d_in[5];
    const float* b1    = (const float*)d_in[6];
    const float* W2    = (const float*)d_in[7];
    const float* b2    = (const float*)d_in[8];
    float* out = (float*)d_out;

    char* ws = (char*)d_ws;
    bf16_t* A1  = (bf16_t*)(ws);                                  // 4096*768  bf16 = 6 MB
    bf16_t* W1t = (bf16_t*)(ws + 6291456);                        // 1024*768  bf16
    bf16_t* W2t = (bf16_t*)(ws + 6291456 + 1572864);              // 256*1024  bf16
    bf16_t* h   = (bf16_t*)(ws + 8388608);                        // 4096*1024 bf16 = 8 MB

    cvt_transpose<<<(HIDDEN_SIZE * INPUT_SIZE + 255) / 256, 256, 0, stream>>>(
        W1, W1t, INPUT_SIZE, HIDDEN_SIZE);
    cvt_transpose<<<(GLOBAL_SIZE * HIDDEN_SIZE + 255) / 256, 256, 0, stream>>>(
        W2, W2t, HIDDEN_SIZE, GLOBAL_SIZE);

    mean_concat_kernel<<<N_GRAPHS, 128, 0, stream>>>(x, u, batch, A1);

    gemm_bt<true, true><<<dim3(N_GRAPHS / 128, HIDDEN_SIZE / 128), 256, 0, stream>>>(
        A1, W1t, b1, h, N_GRAPHS, HIDDEN_SIZE, INPUT_SIZE);
    gemm_bt<false, false><<<dim3(N_GRAPHS / 128, GLOBAL_SIZE / 128), 256, 0, stream>>>(
        h, W2t, b2, out, N_GRAPHS, GLOBAL_SIZE, HIDDEN_SIZE);
}